// Round 2
// baseline (2098.830 us; speedup 1.0000x reference)
//
#include <hip/hip_runtime.h>
#include <math.h>

#define NHEADS 12
#define SEQ 4096
#define BATCH 8
#define HDIM 64

// ---------------- zero small accumulators ----------------
__global__ void zero_kernel(float* p, int n) {
  int i = blockIdx.x * 256 + threadIdx.x;
  if (i < n) p[i] = 0.f;
}

// ---------------- SGEMM: C = A(M x K) * W(Nout x K)^T + bias ----------------
// BM=BN=128, BK=16, 256 threads, 8x8 micro-tile per thread.
// MODE=1: epilogue maps global col (colBase+local) into q/k/v (B,H,N,D), elu+1 on q,k.
// MODE=0: plain row-major out0[m*768+col].
template<int MODE>
__global__ __launch_bounds__(256) void gemm_kernel(
    const float* __restrict__ A, const float* __restrict__ W,
    const float* __restrict__ bias,
    float* __restrict__ out0, float* __restrict__ out1, float* __restrict__ out2,
    int K, int colBase)
{
  __shared__ float As[16 * 128];
  __shared__ float Bs[16 * 128];
  const int t  = threadIdx.x;
  const int m0 = blockIdx.x * 128;
  const int j0 = blockIdx.y * 128;
  const int tx = t & 15;        // 0..15 -> output cols tx*8..
  const int ty = t >> 4;        // 0..15 -> output rows ty*8..
  const int lr = t >> 2;        // 0..63  loader row
  const int lc = (t & 3) << 2;  // 0,4,8,12 loader col4

  float acc[8][8];
#pragma unroll
  for (int i = 0; i < 8; ++i)
#pragma unroll
    for (int j = 0; j < 8; ++j) acc[i][j] = 0.f;

  for (int k0 = 0; k0 < K; k0 += 16) {
    float4 a0 = *(const float4*)&A[(size_t)(m0 + lr) * K + k0 + lc];
    float4 a1 = *(const float4*)&A[(size_t)(m0 + lr + 64) * K + k0 + lc];
    float4 w0 = *(const float4*)&W[(size_t)(colBase + j0 + lr) * K + k0 + lc];
    float4 w1 = *(const float4*)&W[(size_t)(colBase + j0 + lr + 64) * K + k0 + lc];
    __syncthreads();
    As[(lc + 0) * 128 + lr] = a0.x;
    As[(lc + 1) * 128 + lr] = a0.y;
    As[(lc + 2) * 128 + lr] = a0.z;
    As[(lc + 3) * 128 + lr] = a0.w;
    As[(lc + 0) * 128 + lr + 64] = a1.x;
    As[(lc + 1) * 128 + lr + 64] = a1.y;
    As[(lc + 2) * 128 + lr + 64] = a1.z;
    As[(lc + 3) * 128 + lr + 64] = a1.w;
    Bs[(lc + 0) * 128 + lr] = w0.x;
    Bs[(lc + 1) * 128 + lr] = w0.y;
    Bs[(lc + 2) * 128 + lr] = w0.z;
    Bs[(lc + 3) * 128 + lr] = w0.w;
    Bs[(lc + 0) * 128 + lr + 64] = w1.x;
    Bs[(lc + 1) * 128 + lr + 64] = w1.y;
    Bs[(lc + 2) * 128 + lr + 64] = w1.z;
    Bs[(lc + 3) * 128 + lr + 64] = w1.w;
    __syncthreads();
#pragma unroll
    for (int kk = 0; kk < 16; ++kk) {
      float a[8], b[8];
      *(float4*)&a[0] = *(const float4*)&As[kk * 128 + ty * 8];
      *(float4*)&a[4] = *(const float4*)&As[kk * 128 + ty * 8 + 4];
      *(float4*)&b[0] = *(const float4*)&Bs[kk * 128 + tx * 8];
      *(float4*)&b[4] = *(const float4*)&Bs[kk * 128 + tx * 8 + 4];
#pragma unroll
      for (int i = 0; i < 8; ++i)
#pragma unroll
        for (int j = 0; j < 8; ++j) acc[i][j] += a[i] * b[j];
    }
  }

  // epilogue
#pragma unroll
  for (int i = 0; i < 8; ++i) {
    const int m  = m0 + ty * 8 + i;
    const int b_ = m >> 12;       // /4096
    const int n  = m & 4095;
#pragma unroll
    for (int j = 0; j < 8; ++j) {
      const int col = colBase + j0 + tx * 8 + j;
      float val = acc[i][j] + bias[col];
      if (MODE == 1) {
        const int t3  = col / 768;
        const int rem = col - t3 * 768;
        const int h   = rem >> 6;
        const int d   = rem & 63;
        if (t3 < 2) val = (val > 0.f) ? (val + 1.f) : expf(val);  // elu(x)+1
        float* dst = (t3 == 0) ? out0 : ((t3 == 1) ? out1 : out2);
        dst[(((size_t)(b_ * NHEADS + h)) * SEQ + n) * 64 + d] = val;
      } else {
        out0[(size_t)m * 768 + col] = val;
      }
    }
  }
}

// ---------------- kv[b,h,d,e] = sum_n k[b,h,n,d]*v[b,h,n,e]; ksum[b,h,d] ----
// grid (96, 8 N-splits), 256 threads. Each thread: e = lane, d = wave*16+i.
__global__ __launch_bounds__(256) void kv_kernel(
    const float* __restrict__ k, const float* __restrict__ v,
    float* __restrict__ kv, float* __restrict__ ksum)
{
  __shared__ float ks[32 * 64];
  __shared__ float vs[32 * 64];
  const int bh = blockIdx.x;   // 0..95
  const int s  = blockIdx.y;   // 0..7
  const int t  = threadIdx.x;
  const int w  = t >> 6;       // wave 0..3
  const int l  = t & 63;       // lane = e
  const size_t base = (size_t)bh * SEQ * 64 + (size_t)s * 512 * 64;

  float acc[16];
#pragma unroll
  for (int i = 0; i < 16; ++i) acc[i] = 0.f;
  float kspart = 0.f;

  const int nn0 = t >> 4;            // 0..15
  const int c4  = (t & 15) << 2;     // 0..60

  for (int chunk = 0; chunk < 512; chunk += 32) {
    __syncthreads();
    *(float4*)&ks[nn0 * 64 + c4]        = *(const float4*)&k[base + (size_t)(chunk + nn0) * 64 + c4];
    *(float4*)&ks[(nn0 + 16) * 64 + c4] = *(const float4*)&k[base + (size_t)(chunk + nn0 + 16) * 64 + c4];
    *(float4*)&vs[nn0 * 64 + c4]        = *(const float4*)&v[base + (size_t)(chunk + nn0) * 64 + c4];
    *(float4*)&vs[(nn0 + 16) * 64 + c4] = *(const float4*)&v[base + (size_t)(chunk + nn0 + 16) * 64 + c4];
    __syncthreads();
#pragma unroll 4
    for (int nn = 0; nn < 32; ++nn) {
      const float ve = vs[nn * 64 + l];
      const float4* kr = (const float4*)&ks[nn * 64 + w * 16];
      float4 k0 = kr[0], k1 = kr[1], k2 = kr[2], k3 = kr[3];
      acc[0]  += k0.x * ve; acc[1]  += k0.y * ve; acc[2]  += k0.z * ve; acc[3]  += k0.w * ve;
      acc[4]  += k1.x * ve; acc[5]  += k1.y * ve; acc[6]  += k1.z * ve; acc[7]  += k1.w * ve;
      acc[8]  += k2.x * ve; acc[9]  += k2.y * ve; acc[10] += k2.z * ve; acc[11] += k2.w * ve;
      acc[12] += k3.x * ve; acc[13] += k3.y * ve; acc[14] += k3.z * ve; acc[15] += k3.w * ve;
      kspart += ks[nn * 64 + l];
    }
  }
#pragma unroll
  for (int i = 0; i < 16; ++i) {
    const int d = w * 16 + i;
    atomicAdd(&kv[((size_t)bh * 64 + d) * 64 + l], acc[i]);
  }
  if (t < 64) atomicAdd(&ksum[(size_t)bh * 64 + l], kspart);
}

// ---------------- att[b,n,h*64+e] = (q[b,h,n,:].kv[:,e]) / (q.ksum + 1e-6) --
// grid (96, 64 chunks of 64 rows), 256 threads (4 waves x 16 rows).
__global__ __launch_bounds__(256) void attn_kernel(
    const float* __restrict__ q, const float* __restrict__ kv,
    const float* __restrict__ ksum, float* __restrict__ att)
{
  __shared__ float kvs[64 * 64];
  __shared__ float qs[64 * 64];
  __shared__ float ksums[64];
  const int bh = blockIdx.x;   // 0..95
  const int nc = blockIdx.y;   // 0..63
  const int t  = threadIdx.x;
  const int w  = t >> 6;
  const int l  = t & 63;
  const int b_ = bh / NHEADS;
  const int h  = bh - b_ * NHEADS;
  const int n0 = nc * 64;

#pragma unroll
  for (int i = 0; i < 4; ++i) {
    const int idx = t + i * 256;  // float4 index 0..1023
    *(float4*)&kvs[idx * 4] = *(const float4*)&kv[(size_t)bh * 4096 + idx * 4];
    *(float4*)&qs[idx * 4]  = *(const float4*)&q[(size_t)bh * SEQ * 64 + (size_t)n0 * 64 + idx * 4];
  }
  if (t < 64) ksums[t] = ksum[(size_t)bh * 64 + t];
  __syncthreads();

  for (int ni = 0; ni < 16; ++ni) {
    const int nn = w * 16 + ni;
    float acc = 0.f;
#pragma unroll
    for (int c4 = 0; c4 < 16; ++c4) {
      float4 qv = *(const float4*)&qs[nn * 64 + c4 * 4];
      acc += qv.x * kvs[(c4 * 4 + 0) * 64 + l];
      acc += qv.y * kvs[(c4 * 4 + 1) * 64 + l];
      acc += qv.z * kvs[(c4 * 4 + 2) * 64 + l];
      acc += qv.w * kvs[(c4 * 4 + 3) * 64 + l];
    }
    float p = qs[nn * 64 + l] * ksums[l];
#pragma unroll
    for (int off = 32; off > 0; off >>= 1) p += __shfl_xor(p, off, 64);
    const float norm = p + 1e-6f;
    const int n = n0 + nn;
    att[((size_t)(b_ * SEQ + n)) * 768 + h * 64 + l] = acc / norm;
  }
}

extern "C" void kernel_launch(void* const* d_in, const int* in_sizes, int n_in,
                              void* d_out, int out_size, void* d_ws, size_t ws_size,
                              hipStream_t stream)
{
  const float* x     = (const float*)d_in[0];
  const float* Wqkv  = (const float*)d_in[1];
  const float* bqkv  = (const float*)d_in[2];
  const float* Wproj = (const float*)d_in[3];
  const float* bproj = (const float*)d_in[4];
  float* out = (float*)d_out;

  const size_t SZ = (size_t)BATCH * NHEADS * SEQ * 64;  // 25,165,824 floats
  // Workspace layout (peak ~203 MB):
  //   bufK [SZ]   : k, later reused as att
  //   bufV [SZ]   : v, later reused as q
  //   kvb  [96*64*64], ksum [96*64]
  float* bufK = (float*)d_ws;
  float* bufV = bufK + SZ;
  float* kvb  = bufV + SZ;
  float* ksum = kvb + (size_t)96 * 64 * 64;

  // zero kv accumulators (96*64*64 + 96*64 = 399360 = 1560*256)
  zero_kernel<<<1560, 256, 0, stream>>>(kvb, 96 * 64 * 64 + 96 * 64);

  // 1a: K,V columns [768, 2304) of the qkv projection
  dim3 g1a(32768 / 128, 1536 / 128);  // (256, 12)
  gemm_kernel<1><<<g1a, 256, 0, stream>>>(x, Wqkv, bqkv, nullptr, bufK, bufV, 768, 768);

  // kv accumulation (k, v now fully consumed after this)
  kv_kernel<<<dim3(96, 8), 256, 0, stream>>>(bufK, bufV, kvb, ksum);

  // 1b: Q columns [0, 768) -> write q into bufV (v is dead)
  float* q = bufV;
  dim3 g1b(32768 / 128, 768 / 128);   // (256, 6)
  gemm_kernel<1><<<g1b, 256, 0, stream>>>(x, Wqkv, bqkv, q, nullptr, nullptr, 768, 0);

  // attention apply -> att into bufK (k is dead)
  float* att = bufK;
  attn_kernel<<<dim3(96, 64), 256, 0, stream>>>(q, kvb, ksum, att);

  // output projection
  dim3 g2(32768 / 128, 768 / 128);    // (256, 6)
  gemm_kernel<0><<<g2, 256, 0, stream>>>(att, Wproj, bproj, out, nullptr, nullptr, 768, 0);
}

// Round 3
// 617.756 us; speedup vs baseline: 3.3975x; 3.3975x over previous
//
#include <hip/hip_runtime.h>
#include <hip/hip_fp16.h>
#include <math.h>

#define NHEADS 12
#define SEQ 4096
#define BATCH 8

typedef _Float16 half8 __attribute__((ext_vector_type(8)));
typedef float floatx4 __attribute__((ext_vector_type(4)));

// ---------------- zero small accumulators ----------------
__global__ void zero_kernel(float* p, int n) {
  int i = blockIdx.x * 256 + threadIdx.x;
  if (i < n) p[i] = 0.f;
}

// ---------------- fp32 -> fp16 cast, 4 elems/thread ----------------
__global__ void cast_f2h(const float* __restrict__ in, __half* __restrict__ out, int n) {
  int i = (blockIdx.x * 256 + threadIdx.x) * 4;
  if (i < n) {
    float4 v = *(const float4*)&in[i];
    ushort4 o;
    o.x = __half_as_ushort(__float2half(v.x));
    o.y = __half_as_ushort(__float2half(v.y));
    o.z = __half_as_ushort(__float2half(v.z));
    o.w = __half_as_ushort(__float2half(v.w));
    *(ushort4*)&out[i] = o;
  }
}

// Stage a 128x32 f16 tile (8 KB) into LDS via global_load_lds width=16,
// with XOR swizzle: slot(row r, 16B-chunk q): mp=r>>1, p=(r&1)*4+q,
// ps=p^(mp&7), slot=mp*8+ps.  Self-inverse; bank-conflict-free for both
// staging (lane-sequential) and ds_read_b128 fragment reads.
__device__ __forceinline__ void stage_tile(const __half* __restrict__ gbase, int ldg,
                                           _Float16* lds, int t) {
#pragma unroll
  for (int it = 0; it < 2; ++it) {
    const int s  = it * 256 + t;
    const int mp = s >> 3, ps = s & 7;
    const int p  = ps ^ (mp & 7);
    const int r  = mp * 2 + (p >> 2);
    const int q  = p & 3;
    const __half* g = gbase + (size_t)r * ldg + q * 8;
    _Float16* dst = lds + (s >> 6) * 512;   // wave-uniform base, lane lands at +lane*16B
    __builtin_amdgcn_global_load_lds((const __attribute__((address_space(1))) void*)g,
                                     (__attribute__((address_space(3))) void*)dst, 16, 0, 0);
  }
}

__device__ __forceinline__ half8 read_frag(const _Float16* lds, int row, int quad) {
  const int mp = row >> 1;
  const int p  = ((row & 1) << 2) | quad;
  const int ps = p ^ (mp & 7);
  return *(const half8*)(lds + (mp * 8 + ps) * 8);
}

// ---------------- HGEMM: C = A(M x 768) * W(rows x 768)^T + bias ------------
// 128x128 tile, 4 waves (2x2), each 64x64 via 4x4 of mfma_f32_16x16x32_f16.
// MODE=1: epilogue maps col (colBase+local) to q/k/v (B,H,N,D) f16, elu+1 on q,k.
// MODE=0: fp32 row-major outF[m*768+col].
template<int MODE>
__global__ __launch_bounds__(256) void hgemm_kernel(
    const __half* __restrict__ A, const __half* __restrict__ W,
    const float* __restrict__ bias,
    __half* __restrict__ out0, __half* __restrict__ out1, __half* __restrict__ out2,
    float* __restrict__ outF, int colBase)
{
  const int K = 768;
  __shared__ __align__(16) _Float16 As[4096];
  __shared__ __align__(16) _Float16 Bs[4096];
  const int t    = threadIdx.x;
  const int w    = t >> 6;
  const int l    = t & 63;
  const int quad = l >> 4;
  const int mrow = l & 15;
  const int m0   = blockIdx.x * 128;
  const int j0   = blockIdx.y * 128;
  const int wr   = (w >> 1) * 64;   // wave row offset in tile
  const int wc   = (w & 1) * 64;    // wave col offset in tile

  floatx4 acc[4][4];
#pragma unroll
  for (int i = 0; i < 4; ++i)
#pragma unroll
    for (int j = 0; j < 4; ++j) acc[i][j] = (floatx4){0.f, 0.f, 0.f, 0.f};

  for (int k0 = 0; k0 < K; k0 += 32) {
    __syncthreads();
    stage_tile(A + (size_t)m0 * K + k0, K, As, t);
    stage_tile(W + (size_t)(colBase + j0) * K + k0, K, Bs, t);
    __syncthreads();   // forces vmcnt(0) drain of global_load_lds

    half8 af[4], bf[4];
#pragma unroll
    for (int i = 0; i < 4; ++i) af[i] = read_frag(As, wr + i * 16 + mrow, quad);
#pragma unroll
    for (int j = 0; j < 4; ++j) bf[j] = read_frag(Bs, wc + j * 16 + mrow, quad);
#pragma unroll
    for (int i = 0; i < 4; ++i)
#pragma unroll
      for (int j = 0; j < 4; ++j)
        acc[i][j] = __builtin_amdgcn_mfma_f32_16x16x32_f16(af[i], bf[j], acc[i][j], 0, 0, 0);
  }

  // epilogue: C/D layout col=lane&15, row=quad*4+reg
#pragma unroll
  for (int j = 0; j < 4; ++j) {
    const int col = colBase + j0 + wc + j * 16 + mrow;
    const float bsv = bias[col];
    const int t3  = col / 768;
    const int rem = col - t3 * 768;
    const int h   = rem >> 6;
    const int d   = rem & 63;
    __half* dst = (t3 == 0) ? out0 : ((t3 == 1) ? out1 : out2);
#pragma unroll
    for (int i = 0; i < 4; ++i) {
#pragma unroll
      for (int r = 0; r < 4; ++r) {
        const int m  = m0 + wr + i * 16 + quad * 4 + r;
        float val = acc[i][j][r] + bsv;
        if (MODE == 1) {
          const int b_ = m >> 12;
          const int n  = m & 4095;
          if (t3 < 2) val = (val > 0.f) ? (val + 1.f) : expf(val);  // elu(x)+1
          dst[(((size_t)(b_ * NHEADS + h)) * SEQ + n) * 64 + d] = __float2half(val);
        } else {
          outF[(size_t)m * 768 + col] = val;
        }
      }
    }
  }
}

// ---------------- kv[b,h,d,e] = sum_n k[n,d]*v[n,e]; ksum[b,h,d] ------------
__global__ __launch_bounds__(256) void kv_kernel(
    const __half* __restrict__ k, const __half* __restrict__ v,
    float* __restrict__ kv, float* __restrict__ ksum)
{
  __shared__ float ks[32 * 64];
  __shared__ float vs[32 * 64];
  const int bh = blockIdx.x;
  const int s  = blockIdx.y;
  const int t  = threadIdx.x;
  const int w  = t >> 6;
  const int l  = t & 63;
  const size_t base = (size_t)bh * SEQ * 64 + (size_t)s * 512 * 64;

  float acc[16];
#pragma unroll
  for (int i = 0; i < 16; ++i) acc[i] = 0.f;
  float kspart = 0.f;

  const int nn0 = t >> 3;           // 0..31
  const int c8  = (t & 7) * 8;      // 0..56

  for (int chunk = 0; chunk < 512; chunk += 32) {
    __syncthreads();
    {
      half8 kk = *(const half8*)&k[base + (size_t)(chunk + nn0) * 64 + c8];
      half8 vv = *(const half8*)&v[base + (size_t)(chunk + nn0) * 64 + c8];
#pragma unroll
      for (int e = 0; e < 8; ++e) {
        ks[nn0 * 64 + c8 + e] = (float)kk[e];
        vs[nn0 * 64 + c8 + e] = (float)vv[e];
      }
    }
    __syncthreads();
#pragma unroll 4
    for (int nn = 0; nn < 32; ++nn) {
      const float ve = vs[nn * 64 + l];
      const float4* kr = (const float4*)&ks[nn * 64 + w * 16];
      float4 k0 = kr[0], k1 = kr[1], k2 = kr[2], k3 = kr[3];
      acc[0]  += k0.x * ve; acc[1]  += k0.y * ve; acc[2]  += k0.z * ve; acc[3]  += k0.w * ve;
      acc[4]  += k1.x * ve; acc[5]  += k1.y * ve; acc[6]  += k1.z * ve; acc[7]  += k1.w * ve;
      acc[8]  += k2.x * ve; acc[9]  += k2.y * ve; acc[10] += k2.z * ve; acc[11] += k2.w * ve;
      acc[12] += k3.x * ve; acc[13] += k3.y * ve; acc[14] += k3.z * ve; acc[15] += k3.w * ve;
      kspart += ks[nn * 64 + l];
    }
  }
#pragma unroll
  for (int i = 0; i < 16; ++i) {
    const int d = w * 16 + i;
    atomicAdd(&kv[((size_t)bh * 64 + d) * 64 + l], acc[i]);
  }
  if (t < 64) atomicAdd(&ksum[(size_t)bh * 64 + l], kspart);
}

// ---- att[b,n,h*64+e] = (q[b,h,n,:].kv[:,e]) / (q.ksum + 1e-6), f16 out ----
__global__ __launch_bounds__(256) void attn_kernel(
    const __half* __restrict__ q, const float* __restrict__ kv,
    const float* __restrict__ ksum, __half* __restrict__ att)
{
  __shared__ float kvs[64 * 64];
  __shared__ float qs[64 * 64];
  __shared__ float ksums[64];
  const int bh = blockIdx.x;
  const int nc = blockIdx.y;
  const int t  = threadIdx.x;
  const int w  = t >> 6;
  const int l  = t & 63;
  const int b_ = bh / NHEADS;
  const int h  = bh - b_ * NHEADS;
  const int n0 = nc * 64;

#pragma unroll
  for (int i = 0; i < 4; ++i) {
    const int idx = t + i * 256;
    *(float4*)&kvs[idx * 4] = *(const float4*)&kv[(size_t)bh * 4096 + idx * 4];
  }
#pragma unroll
  for (int i = 0; i < 2; ++i) {
    const int idx = t + i * 256;  // half8 chunk 0..511
    half8 qq = *(const half8*)&q[(size_t)bh * SEQ * 64 + (size_t)n0 * 64 + idx * 8];
#pragma unroll
    for (int e = 0; e < 8; ++e) qs[idx * 8 + e] = (float)qq[e];
  }
  if (t < 64) ksums[t] = ksum[(size_t)bh * 64 + t];
  __syncthreads();

  for (int ni = 0; ni < 16; ++ni) {
    const int nn = w * 16 + ni;
    float acc = 0.f;
#pragma unroll
    for (int c4 = 0; c4 < 16; ++c4) {
      float4 qv = *(const float4*)&qs[nn * 64 + c4 * 4];
      acc += qv.x * kvs[(c4 * 4 + 0) * 64 + l];
      acc += qv.y * kvs[(c4 * 4 + 1) * 64 + l];
      acc += qv.z * kvs[(c4 * 4 + 2) * 64 + l];
      acc += qv.w * kvs[(c4 * 4 + 3) * 64 + l];
    }
    float p = qs[nn * 64 + l] * ksums[l];
#pragma unroll
    for (int off = 32; off > 0; off >>= 1) p += __shfl_xor(p, off, 64);
    const float norm = p + 1e-6f;
    const int n = n0 + nn;
    att[((size_t)(b_ * SEQ + n)) * 768 + h * 64 + l] = __float2half(acc / norm);
  }
}

extern "C" void kernel_launch(void* const* d_in, const int* in_sizes, int n_in,
                              void* d_out, int out_size, void* d_ws, size_t ws_size,
                              hipStream_t stream)
{
  const float* x     = (const float*)d_in[0];
  const float* Wqkv  = (const float*)d_in[1];
  const float* bqkv  = (const float*)d_in[2];
  const float* Wproj = (const float*)d_in[3];
  const float* bproj = (const float*)d_in[4];
  float* out = (float*)d_out;

  const size_t SZ = (size_t)BATCH * NHEADS * SEQ * 64;  // 25,165,824
  // Workspace (peak ~157 MB): xh | Wqh | Wph | R3 (k -> q) | R4 (v -> att) | kv | ksum
  __half* xh  = (__half*)d_ws;
  __half* Wqh = xh + SZ;
  __half* Wph = Wqh + (size_t)2304 * 768;
  __half* R3  = Wph + (size_t)768 * 768;
  __half* R4  = R3 + SZ;
  float*  kvb = (float*)(R4 + SZ);
  float*  ksum = kvb + 96 * 64 * 64;

  zero_kernel<<<1560, 256, 0, stream>>>(kvb, 96 * 64 * 64 + 96 * 64);

  cast_f2h<<<(int)(SZ / 1024), 256, 0, stream>>>(x, xh, (int)SZ);
  cast_f2h<<<(2304 * 768) / 1024, 256, 0, stream>>>(Wqkv, Wqh, 2304 * 768);
  cast_f2h<<<(768 * 768) / 1024, 256, 0, stream>>>(Wproj, Wph, 768 * 768);

  // K,V columns [768, 2304): k -> R3, v -> R4
  hgemm_kernel<1><<<dim3(256, 12), 256, 0, stream>>>(
      xh, Wqh, bqkv, nullptr, R3, R4, nullptr, 768);

  kv_kernel<<<dim3(96, 8), 256, 0, stream>>>(R3, R4, kvb, ksum);

  // Q columns [0, 768): q -> R3 (k dead)
  hgemm_kernel<1><<<dim3(256, 6), 256, 0, stream>>>(
      xh, Wqh, bqkv, R3, nullptr, nullptr, nullptr, 0);

  // attention apply: att -> R4 (v dead)
  attn_kernel<<<dim3(96, 64), 256, 0, stream>>>(R3, kvb, ksum, R4);

  // output projection: fp32 out
  hgemm_kernel<0><<<dim3(256, 6), 256, 0, stream>>>(
      R4, Wph, bproj, nullptr, nullptr, nullptr, out, 0);
}

// Round 4
// 508.459 us; speedup vs baseline: 4.1278x; 1.2150x over previous
//
#include <hip/hip_runtime.h>
#include <hip/hip_fp16.h>
#include <math.h>

#define NHEADS 12
#define SEQ 4096
#define BATCH 8

typedef _Float16 half8 __attribute__((ext_vector_type(8)));
typedef float floatx4 __attribute__((ext_vector_type(4)));

// ---------------- zero small accumulators ----------------
__global__ void zero_kernel(float* p, int n) {
  int i = blockIdx.x * 256 + threadIdx.x;
  if (i < n) p[i] = 0.f;
}

// ---------------- fp32 -> fp16 cast, 4 elems/thread ----------------
__global__ void cast_f2h(const float* __restrict__ in, __half* __restrict__ out, int n) {
  int i = (blockIdx.x * 256 + threadIdx.x) * 4;
  if (i < n) {
    float4 v = *(const float4*)&in[i];
    ushort4 o;
    o.x = __half_as_ushort(__float2half(v.x));
    o.y = __half_as_ushort(__float2half(v.y));
    o.z = __half_as_ushort(__float2half(v.z));
    o.w = __half_as_ushort(__float2half(v.w));
    *(ushort4*)&out[i] = o;
  }
}

// ---- 128x32 f16 staging tile via global_load_lds (16B), XOR swizzle ----
__device__ __forceinline__ void stage_tile(const __half* __restrict__ gbase, int ldg,
                                           _Float16* lds, int t) {
#pragma unroll
  for (int it = 0; it < 2; ++it) {
    const int s  = it * 256 + t;
    const int mp = s >> 3, ps = s & 7;
    const int p  = ps ^ (mp & 7);
    const int r  = mp * 2 + (p >> 2);
    const int q  = p & 3;
    const __half* g = gbase + (size_t)r * ldg + q * 8;
    _Float16* dst = lds + (s >> 6) * 512;
    __builtin_amdgcn_global_load_lds((const __attribute__((address_space(1))) void*)g,
                                     (__attribute__((address_space(3))) void*)dst, 16, 0, 0);
  }
}
__device__ __forceinline__ half8 read_frag(const _Float16* lds, int row, int quad) {
  const int mp = row >> 1;
  const int p  = ((row & 1) << 2) | quad;
  const int ps = p ^ (mp & 7);
  return *(const half8*)(lds + (mp * 8 + ps) * 8);
}

// ---- L64: 64x64 f16 tile, row-major with XOR swizzle on 16B chunks ----
// element (row,col) at half-index: row*64 + ((col>>3 ^ (row&7))<<3) + (col&7)
__device__ __forceinline__ void write_l64(_Float16* lds, int row, int col, float v) {
  lds[row * 64 + ((((col >> 3) ^ (row & 7))) << 3) + (col & 7)] = (_Float16)v;
}
__device__ __forceinline__ half8 read_l64c(const _Float16* lds, int row, int c) {
  return *(const half8*)(lds + row * 64 + ((c ^ (row & 7)) << 3));
}

// ---------------- HGEMM: C = A(M x 768) * W(rows x 768)^T + bias ------------
// 128x128 tile, 4 waves (2x2), each 64x64 via 4x4 mfma_f32_16x16x32_f16.
// MODE=1 (KV): col in [768,2304); k tiles get elu+1; f16 out via LDS-transposed
//              coalesced stores into (B,H,N,D).
// MODE=0 (proj): fp32 row-major outF[m*768+col].
template<int MODE>
__global__ __launch_bounds__(256) void hgemm_kernel(
    const __half* __restrict__ A, const __half* __restrict__ W,
    const float* __restrict__ bias,
    __half* __restrict__ outK, __half* __restrict__ outV,
    float* __restrict__ outF, int colBase)
{
  const int K = 768;
  __shared__ __align__(16) _Float16 sh[16384];  // As|Bs (16KB) U epilogue scratch (32KB)
  _Float16* As = sh;
  _Float16* Bs = sh + 4096;
  const int t    = threadIdx.x;
  const int w    = t >> 6;
  const int l    = t & 63;
  const int quad = l >> 4;
  const int mrow = l & 15;
  const int m0   = blockIdx.x * 128;
  const int j0   = blockIdx.y * 128;
  const int wr   = (w >> 1) * 64;
  const int wc   = (w & 1) * 64;

  floatx4 acc[4][4];
#pragma unroll
  for (int i = 0; i < 4; ++i)
#pragma unroll
    for (int j = 0; j < 4; ++j) acc[i][j] = (floatx4){0.f, 0.f, 0.f, 0.f};

  for (int k0 = 0; k0 < K; k0 += 32) {
    __syncthreads();
    stage_tile(A + (size_t)m0 * K + k0, K, As, t);
    stage_tile(W + (size_t)(colBase + j0) * K + k0, K, Bs, t);
    __syncthreads();
    half8 af[4], bf[4];
#pragma unroll
    for (int i = 0; i < 4; ++i) af[i] = read_frag(As, wr + i * 16 + mrow, quad);
#pragma unroll
    for (int j = 0; j < 4; ++j) bf[j] = read_frag(Bs, wc + j * 16 + mrow, quad);
#pragma unroll
    for (int i = 0; i < 4; ++i)
#pragma unroll
      for (int j = 0; j < 4; ++j)
        acc[i][j] = __builtin_amdgcn_mfma_f32_16x16x32_f16(af[i], bf[j], acc[i][j], 0, 0, 0);
  }

  if (MODE == 0) {
    // fp32 row-major: 16 lanes x 4B = 64B full-line segments, no RMW
#pragma unroll
    for (int j = 0; j < 4; ++j) {
      const int col = colBase + j0 + wc + j * 16 + mrow;
      const float bsv = bias[col];
#pragma unroll
      for (int i = 0; i < 4; ++i)
#pragma unroll
        for (int r = 0; r < 4; ++r) {
          const int m = m0 + wr + i * 16 + quad * 4 + r;
          outF[(size_t)m * 768 + col] = acc[i][j][r] + bsv;
        }
    }
    return;
  }

  // MODE==1: wave tile = one head's 64 cols of k or v
  const int col0 = colBase + j0 + wc;          // 64-aligned
  const int t3   = col0 / 768;                 // 1=k, 2=v
  const int h    = (col0 - t3 * 768) >> 6;
  __half* dst    = (t3 == 1) ? outK : outV;
  const int m0w  = m0 + wr;
  const int b_   = m0w >> 12;
  const int n0w  = m0w & 4095;
  _Float16* scr  = sh + w * 4096;              // 8KB per wave

  __syncthreads();   // all As/Bs reads done before scratch overwrites them
#pragma unroll
  for (int j = 0; j < 4; ++j) {
    const int col = j * 16 + mrow;
    const float bsv = bias[col0 + col];
#pragma unroll
    for (int i = 0; i < 4; ++i)
#pragma unroll
      for (int r = 0; r < 4; ++r) {
        const int row = i * 16 + quad * 4 + r;
        float val = acc[i][j][r] + bsv;
        if (t3 == 1) val = (val > 0.f) ? (val + 1.f) : expf(val);  // elu(x)+1
        write_l64(scr, row, col, val);
      }
  }
  __syncthreads();
  const size_t gb = ((size_t)(b_ * NHEADS + h) * SEQ + n0w) * 64;
#pragma unroll
  for (int it = 0; it < 8; ++it) {
    const int row = it * 8 + (l >> 3);
    const int c   = l & 7;
    half8 vv = read_l64c(scr, row, c);
    *(half8*)((_Float16*)dst + gb + (size_t)row * 64 + c * 8) = vv;
  }
}

// ---------------- kv[b,h,d,e] = sum_n k[n,d]*v[n,e]; ksum[b,h,d] ------------
__global__ __launch_bounds__(256) void kv_kernel(
    const __half* __restrict__ k, const __half* __restrict__ v,
    float* __restrict__ kv, float* __restrict__ ksum)
{
  __shared__ float ks[32 * 64];
  __shared__ float vs[32 * 64];
  const int bh = blockIdx.x;
  const int s  = blockIdx.y;
  const int t  = threadIdx.x;
  const int w  = t >> 6;
  const int l  = t & 63;
  const size_t base = (size_t)bh * SEQ * 64 + (size_t)s * 512 * 64;

  float acc[16];
#pragma unroll
  for (int i = 0; i < 16; ++i) acc[i] = 0.f;
  float kspart = 0.f;

  const int nn0 = t >> 3;
  const int c8  = (t & 7) * 8;

  for (int chunk = 0; chunk < 512; chunk += 32) {
    __syncthreads();
    {
      half8 kk = *(const half8*)&k[base + (size_t)(chunk + nn0) * 64 + c8];
      half8 vv = *(const half8*)&v[base + (size_t)(chunk + nn0) * 64 + c8];
#pragma unroll
      for (int e = 0; e < 8; ++e) {
        ks[nn0 * 64 + c8 + e] = (float)kk[e];
        vs[nn0 * 64 + c8 + e] = (float)vv[e];
      }
    }
    __syncthreads();
#pragma unroll 4
    for (int nn = 0; nn < 32; ++nn) {
      const float ve = vs[nn * 64 + l];
      const float4* kr = (const float4*)&ks[nn * 64 + w * 16];
      float4 k0 = kr[0], k1 = kr[1], k2 = kr[2], k3 = kr[3];
      acc[0]  += k0.x * ve; acc[1]  += k0.y * ve; acc[2]  += k0.z * ve; acc[3]  += k0.w * ve;
      acc[4]  += k1.x * ve; acc[5]  += k1.y * ve; acc[6]  += k1.z * ve; acc[7]  += k1.w * ve;
      acc[8]  += k2.x * ve; acc[9]  += k2.y * ve; acc[10] += k2.z * ve; acc[11] += k2.w * ve;
      acc[12] += k3.x * ve; acc[13] += k3.y * ve; acc[14] += k3.z * ve; acc[15] += k3.w * ve;
      kspart += ks[nn * 64 + l];
    }
  }
#pragma unroll
  for (int i = 0; i < 16; ++i) {
    const int d = w * 16 + i;
    atomicAdd(&kv[((size_t)bh * 64 + d) * 64 + l], acc[i]);
  }
  if (t < 64) atomicAdd(&ksum[(size_t)bh * 64 + l], kspart);
}

// ------- fused Q-GEMM + attention apply -------
// grid (256 m-blocks, 6 j-blocks of 128 q-cols = 2 heads). Per wave:
// q-tile 64(n) x 64(d) -> LDS(L64) -> MFMA with kvT head tile -> /norm -> att f16.
__global__ __launch_bounds__(256) void qattn_kernel(
    const __half* __restrict__ A, const __half* __restrict__ W,
    const float* __restrict__ bias,
    const float* __restrict__ kvg, const float* __restrict__ ksumg,
    __half* __restrict__ att)
{
  const int K = 768;
  __shared__ __align__(16) _Float16 sh[24576];  // 48 KB
  _Float16* As = sh;                 // [0,4096)   halfs (main loop)
  _Float16* Bs = sh + 4096;          // [4096,8192)
  // epilogue: qtile wave w at sh + w*4096 ([0,16384)), kvT heads at [16384,24576)
  __shared__ float norms[256];
  __shared__ float ksums[128];
  const int t    = threadIdx.x;
  const int w    = t >> 6;
  const int l    = t & 63;
  const int quad = l >> 4;
  const int mrow = l & 15;
  const int m0   = blockIdx.x * 128;
  const int j0   = blockIdx.y * 128;
  const int wr   = (w >> 1) * 64;
  const int wc   = (w & 1) * 64;
  const int b_   = m0 >> 12;
  const int h0   = j0 >> 6;          // first of 2 heads in this block

  // stage kvT (f16, L64, [e][d]) + ksum for the 2 heads (kv layout is [d][e])
  {
    _Float16* kvT0 = sh + 16384;
#pragma unroll
    for (int ii = 0; ii < 32; ++ii) {
      const int gidx = ii * 256 + t;          // 0..8191
      const int head = gidx >> 12;
      const int r    = gidx & 4095;           // d*64+e
      const float val = kvg[(size_t)(b_ * NHEADS + h0 + head) * 4096 + r];
      write_l64(kvT0 + head * 4096, r & 63, r >> 6, val);
    }
    if (t < 128) ksums[t] = ksumg[(size_t)(b_ * NHEADS + h0 + (t >> 6)) * 64 + (t & 63)];
  }

  floatx4 acc[4][4];
#pragma unroll
  for (int i = 0; i < 4; ++i)
#pragma unroll
    for (int j = 0; j < 4; ++j) acc[i][j] = (floatx4){0.f, 0.f, 0.f, 0.f};

  for (int k0 = 0; k0 < K; k0 += 32) {
    __syncthreads();
    stage_tile(A + (size_t)m0 * K + k0, K, As, t);
    stage_tile(W + (size_t)j0 * K + k0, K, Bs, t);
    __syncthreads();
    half8 af[4], bf[4];
#pragma unroll
    for (int i = 0; i < 4; ++i) af[i] = read_frag(As, wr + i * 16 + mrow, quad);
#pragma unroll
    for (int j = 0; j < 4; ++j) bf[j] = read_frag(Bs, wc + j * 16 + mrow, quad);
#pragma unroll
    for (int i = 0; i < 4; ++i)
#pragma unroll
      for (int j = 0; j < 4; ++j)
        acc[i][j] = __builtin_amdgcn_mfma_f32_16x16x32_f16(af[i], bf[j], acc[i][j], 0, 0, 0);
  }

  _Float16* qtile = sh + w * 4096;
  const _Float16* kvT = sh + 16384 + (w & 1) * 4096;
  const int hh = w & 1;

  __syncthreads();  // main-loop LDS reads done
  // phase 1: q = elu(acc+bias)+1 -> f16 L64
#pragma unroll
  for (int j = 0; j < 4; ++j) {
    const int col = j * 16 + mrow;           // = d
    const float bsv = bias[j0 + wc + col];
#pragma unroll
    for (int i = 0; i < 4; ++i)
#pragma unroll
      for (int r = 0; r < 4; ++r) {
        const int row = i * 16 + quad * 4 + r;
        float val = acc[i][j][r] + bsv;
        val = (val > 0.f) ? (val + 1.f) : expf(val);
        write_l64(qtile, row, col, val);
      }
  }
  __syncthreads();

  // phase 2: reciprocal normalizer per row (lane l -> row l of this wave's tile)
  {
    float nrm = 0.f;
#pragma unroll
    for (int c = 0; c < 8; ++c) {
      half8 qv = read_l64c(qtile, l, c);
#pragma unroll
      for (int e = 0; e < 8; ++e) nrm += (float)qv[e] * ksums[hh * 64 + c * 8 + e];
    }
    norms[w * 64 + l] = 1.f / (nrm + 1e-6f);
  }

  // phase 3: att = q @ kvT^T  (A rows = n, B rows = e, k = d = 64)
  floatx4 oacc[4][4];
#pragma unroll
  for (int i = 0; i < 4; ++i)
#pragma unroll
    for (int j = 0; j < 4; ++j) oacc[i][j] = (floatx4){0.f, 0.f, 0.f, 0.f};
#pragma unroll
  for (int ks = 0; ks < 2; ++ks) {
    half8 af[4], bf[4];
#pragma unroll
    for (int i = 0; i < 4; ++i) af[i] = read_l64c(qtile, i * 16 + mrow, ks * 4 + quad);
#pragma unroll
    for (int j = 0; j < 4; ++j) bf[j] = read_l64c(kvT, j * 16 + mrow, ks * 4 + quad);
#pragma unroll
    for (int i = 0; i < 4; ++i)
#pragma unroll
      for (int j = 0; j < 4; ++j)
        oacc[i][j] = __builtin_amdgcn_mfma_f32_16x16x32_f16(af[i], bf[j], oacc[i][j], 0, 0, 0);
  }
  __syncthreads();  // all qtile/kvT reads + norms writes done

  // phase 4: scale by 1/norm, transpose via qtile region, coalesced store
#pragma unroll
  for (int i = 0; i < 4; ++i)
#pragma unroll
    for (int r = 0; r < 4; ++r) {
      const int row = i * 16 + quad * 4 + r;
      const float rn = norms[w * 64 + row];
#pragma unroll
      for (int j = 0; j < 4; ++j)
        write_l64(qtile, row, j * 16 + mrow, oacc[i][j][r] * rn);
    }
  __syncthreads();
  const int n0w = (m0 & 4095) + wr;
  const size_t abase = (size_t)(b_ * SEQ + n0w) * 768 + (h0 + hh) * 64;
#pragma unroll
  for (int it = 0; it < 8; ++it) {
    const int row = it * 8 + (l >> 3);
    const int c   = l & 7;
    half8 vv = read_l64c(qtile, row, c);
    *(half8*)((_Float16*)att + abase + (size_t)row * 768 + c * 8) = vv;
  }
}

extern "C" void kernel_launch(void* const* d_in, const int* in_sizes, int n_in,
                              void* d_out, int out_size, void* d_ws, size_t ws_size,
                              hipStream_t stream)
{
  const float* x     = (const float*)d_in[0];
  const float* Wqkv  = (const float*)d_in[1];
  const float* bqkv  = (const float*)d_in[2];
  const float* Wproj = (const float*)d_in[3];
  const float* bproj = (const float*)d_in[4];
  float* out = (float*)d_out;

  const size_t SZ = (size_t)BATCH * NHEADS * SEQ * 64;  // 25,165,824
  __half* xh  = (__half*)d_ws;
  __half* Wqh = xh + SZ;
  __half* Wph = Wqh + (size_t)2304 * 768;
  __half* R3  = Wph + (size_t)768 * 768;   // k -> att
  __half* R4  = R3 + SZ;                   // v
  float*  kvb = (float*)(R4 + SZ);
  float*  ksum = kvb + 96 * 64 * 64;

  zero_kernel<<<1560, 256, 0, stream>>>(kvb, 96 * 64 * 64 + 96 * 64);

  cast_f2h<<<(int)(SZ / 1024), 256, 0, stream>>>(x, xh, (int)SZ);
  cast_f2h<<<(2304 * 768) / 1024, 256, 0, stream>>>(Wqkv, Wqh, 2304 * 768);
  cast_f2h<<<(768 * 768) / 1024, 256, 0, stream>>>(Wproj, Wph, 768 * 768);

  // K,V columns [768, 2304): k -> R3, v -> R4
  hgemm_kernel<1><<<dim3(256, 12), 256, 0, stream>>>(
      xh, Wqh, bqkv, R3, R4, nullptr, 768);

  kv_kernel<<<dim3(96, 8), 256, 0, stream>>>(R3, R4, kvb, ksum);

  // fused Q-GEMM + attention: att -> R3 (k dead after kv_kernel)
  qattn_kernel<<<dim3(256, 6), 256, 0, stream>>>(
      xh, Wqh, bqkv, kvb, ksum, R3);

  // output projection: fp32 out
  hgemm_kernel<0><<<dim3(256, 6), 256, 0, stream>>>(
      R3, Wph, bproj, nullptr, nullptr, out, 0);
}